// Round 1
// baseline (1632.565 us; speedup 1.0000x reference)
//
#include <hip/hip_runtime.h>
#include <hip/hip_bf16.h>

// bf16 MFMA fragment types (per cdna_hip_programming.md §3, compile-verified on gfx950)
typedef __attribute__((ext_vector_type(8))) short bf16x8;
typedef __attribute__((ext_vector_type(4))) float floatx4;
typedef __attribute__((ext_vector_type(4))) short short4v;

__device__ inline short f2bf(float f) {
  union { float f; unsigned u; } v; v.f = f;
  unsigned r = v.u + 0x7fffu + ((v.u >> 16) & 1u);  // round-to-nearest-even
  return (short)(r >> 16);
}

// ---------------- Kernel 0: fp32 -> bf16 conversion (x and the 3 weight mats)
// NX = 8*2048*1024 = 16777216 ; each W = 1048576
__global__ __launch_bounds__(256) void cvt_kernel(
    const float* __restrict__ x, const float* __restrict__ wq,
    const float* __restrict__ wk, const float* __restrict__ wv,
    short* __restrict__ Xb, short* __restrict__ Wb) {
  long i4 = (long)(blockIdx.x * 256 + threadIdx.x) * 4;
  const float* src; short* dst; long off;
  if (i4 < 16777216L) {
    src = x; dst = Xb; off = i4;
  } else {
    long j = i4 - 16777216L;
    int mat = (int)(j >> 20);
    src = (mat == 0) ? wq : ((mat == 1) ? wk : wv);
    dst = Wb + ((long)mat << 20);
    off = j & 1048575L;
  }
  float4 v = *(const float4*)(src + off);
  short4v o; o.x = f2bf(v.x); o.y = f2bf(v.y); o.z = f2bf(v.z); o.w = f2bf(v.w);
  *(short4v*)(dst + off) = o;
}

// ---------------- Kernel 1: QKV projection  y[m,n] = sum_k X[m,k] * W[n,k] + b[n]
// NT-GEMM: both operands K-contiguous. 64x64 tile / block (4 waves, wave = 16 rows x 64 cols).
// mat 0 (Q): scaled by 1/32, row-major bf16. mat 1 (K): row-major bf16.
// mat 2 (V): written TRANSPOSED per batch: Vtb[b][c][t].
__global__ __launch_bounds__(256) void qkv_gemm(
    const short* __restrict__ Xb, const short* __restrict__ Wb,
    const float* __restrict__ bq, const float* __restrict__ bk,
    const float* __restrict__ bv,
    short* __restrict__ Qb, short* __restrict__ Kb, short* __restrict__ Vtb) {
  const int nt  = blockIdx.x & 15;
  const int mat = blockIdx.x >> 4;
  const int mt  = blockIdx.y;
  const int wave = threadIdx.x >> 6;
  const int lane = threadIdx.x & 63;
  const int quad = lane >> 4, l16 = lane & 15;

  const int row0 = mt * 64 + wave * 16;
  const int col0 = nt * 64;
  const short* A  = Xb + (size_t)(row0 + l16) * 1024 + quad * 8;
  const short* Bp = Wb + ((size_t)mat << 20) + (size_t)(col0 + l16) * 1024 + quad * 8;

  floatx4 acc[4] = {};
  for (int k = 0; k < 1024; k += 32) {
    bf16x8 af = *(const bf16x8*)(A + k);
#pragma unroll
    for (int nb = 0; nb < 4; nb++) {
      bf16x8 bf = *(const bf16x8*)(Bp + k + nb * 16384);
      acc[nb] = __builtin_amdgcn_mfma_f32_16x16x32_bf16(af, bf, acc[nb], 0, 0, 0);
    }
  }
  const float* bias = (mat == 0) ? bq : (mat == 1) ? bk : bv;
  const float qs = (mat == 0) ? 0.03125f : 1.0f;  // fold 1/sqrt(C) into Q
#pragma unroll
  for (int nb = 0; nb < 4; nb++) {
    const int col = col0 + nb * 16 + l16;
    const float bb = bias[col];
#pragma unroll
    for (int r = 0; r < 4; r++) {
      const int row = row0 + quad * 4 + r;  // C/D layout: row=(lane>>4)*4+reg, col=lane&15
      short o = f2bf((acc[nb][r] + bb) * qs);
      if (mat == 0)      Qb[(size_t)row * 1024 + col] = o;
      else if (mat == 1) Kb[(size_t)row * 1024 + col] = o;
      else {
        int bat = row >> 11, t = row & 2047;
        Vtb[((size_t)bat << 21) + (size_t)col * 2048 + t] = o;
      }
    }
  }
}

// ---------------- Kernel 2: flash attention, causal. Block = 512 thr (8 waves).
// Q-tile = 32 rows, KV-tile = 64. Wave w: QK^T tile (mi=w&1, ni=w>>1); PV cols [w*128, w*128+128).
__global__ __launch_bounds__(512) void flash_attn(
    const short* __restrict__ Qb, const short* __restrict__ Kb,
    const short* __restrict__ Vtb, float* __restrict__ out) {
  __shared__ float Sf[32][66];
  __shared__ short Pb[32][72];
  __shared__ float mrow[32], lrow[32], arow[32];
  __shared__ float red[32][16];

  const int b  = blockIdx.x & 7;
  const int qt = 63 - (blockIdx.x >> 3);  // heavy (late) q-tiles first: causal load balance
  const int qbase = qt * 32;
  const int tid = threadIdx.x;
  const int wave = tid >> 6, lane = tid & 63;
  const int quad = lane >> 4, l16 = lane & 15;

  const short* Qp = Qb + ((size_t)b << 21);
  const short* Kp = Kb + ((size_t)b << 21);
  const short* Vp = Vtb + ((size_t)b << 21);

  if (tid < 32) { mrow[tid] = -1e30f; lrow[tid] = 0.0f; }

  floatx4 O[2][8] = {};

  const int mi = wave & 1, ni = wave >> 1;
  const short* qptr  = Qp + (size_t)(qbase + mi * 16 + l16) * 1024 + quad * 8;
  const short* kptr0 = Kp + (size_t)(ni * 16 + l16) * 1024 + quad * 8;

  const int row = tid >> 4, sub = tid & 15;
  const int gr = qbase + row;
  const int ntiles = (qbase + 31) / 64 + 1;
  const int vc0 = wave * 128;

  __syncthreads();

  for (int kt = 0; kt < ntiles; kt++) {
    const int kvbase = kt * 64;
    // ---- S = (Q/32) K^T : each wave one 16x16 tile, loop over d
    floatx4 s4 = {};
    const short* kptr = kptr0 + (size_t)kvbase * 1024;
#pragma unroll 4
    for (int d = 0; d < 1024; d += 32) {
      bf16x8 qa = *(const bf16x8*)(qptr + d);
      bf16x8 kb = *(const bf16x8*)(kptr + d);
      s4 = __builtin_amdgcn_mfma_f32_16x16x32_bf16(qa, kb, s4, 0, 0, 0);
    }
#pragma unroll
    for (int r = 0; r < 4; r++)
      Sf[mi * 16 + quad * 4 + r][ni * 16 + l16] = s4[r];
    __syncthreads();  // B0

    // ---- online softmax: thread -> (row = tid>>4, 4 cols)
    float sv[4], mx = -1e30f;
#pragma unroll
    for (int j = 0; j < 4; j++) {
      const int c = sub * 4 + j;
      float v = Sf[row][c];
      if (kvbase + c > gr) v = -1e30f;  // causal mask
      sv[j] = v;
      mx = fmaxf(mx, v);
    }
    red[row][sub] = mx;
    __syncthreads();  // B1
    if (sub == 0) {
      float mo = mrow[row], mn = mo;
#pragma unroll
      for (int k2 = 0; k2 < 16; k2++) mn = fmaxf(mn, red[row][k2]);
      mrow[row] = mn;
      arow[row] = __expf(mo - mn);
    }
    __syncthreads();  // B2
    const float mn = mrow[row];
    float ps = 0.0f;
#pragma unroll
    for (int j = 0; j < 4; j++) {
      float p = __expf(sv[j] - mn);
      ps += p;
      Pb[row][sub * 4 + j] = f2bf(p);
    }
    red[row][sub] = ps;
    __syncthreads();  // B3
    if (sub == 0) {
      float s = 0.0f;
#pragma unroll
      for (int k2 = 0; k2 < 16; k2++) s += red[row][k2];
      lrow[row] = lrow[row] * arow[row] + s;
    }
    __syncthreads();  // B4: Pb + arow ready for all waves

    // ---- O = diag(alpha) O + P V  (wave owns 128 V columns; V is pre-transposed)
    float al[2][4];
#pragma unroll
    for (int m2 = 0; m2 < 2; m2++)
#pragma unroll
      for (int r = 0; r < 4; r++)
        al[m2][r] = arow[m2 * 16 + quad * 4 + r];
#pragma unroll
    for (int m2 = 0; m2 < 2; m2++)
#pragma unroll
      for (int nb = 0; nb < 8; nb++)
#pragma unroll
        for (int r = 0; r < 4; r++)
          O[m2][nb][r] *= al[m2][r];

#pragma unroll
    for (int kc = 0; kc < 2; kc++) {
      bf16x8 pa0 = *(const bf16x8*)&Pb[l16][kc * 32 + quad * 8];
      bf16x8 pa1 = *(const bf16x8*)&Pb[16 + l16][kc * 32 + quad * 8];
#pragma unroll
      for (int nb = 0; nb < 8; nb++) {
        const short* vptr = Vp + (size_t)(vc0 + nb * 16 + l16) * 2048 + kvbase + kc * 32 + quad * 8;
        bf16x8 vb = *(const bf16x8*)vptr;
        O[0][nb] = __builtin_amdgcn_mfma_f32_16x16x32_bf16(pa0, vb, O[0][nb], 0, 0, 0);
        O[1][nb] = __builtin_amdgcn_mfma_f32_16x16x32_bf16(pa1, vb, O[1][nb], 0, 0, 0);
      }
    }
  }

  __syncthreads();
  float linv[2][4];
#pragma unroll
  for (int m2 = 0; m2 < 2; m2++)
#pragma unroll
    for (int r = 0; r < 4; r++)
      linv[m2][r] = 1.0f / lrow[m2 * 16 + quad * 4 + r];
#pragma unroll
  for (int m2 = 0; m2 < 2; m2++)
#pragma unroll
    for (int nb = 0; nb < 8; nb++)
#pragma unroll
      for (int r = 0; r < 4; r++) {
        const int rr = qbase + m2 * 16 + quad * 4 + r;
        const int cc = vc0 + nb * 16 + l16;
        out[((size_t)b * 2048 + rr) * 1024 + cc] = O[m2][nb][r] * linv[m2][r];
      }
}

extern "C" void kernel_launch(void* const* d_in, const int* in_sizes, int n_in,
                              void* d_out, int out_size, void* d_ws, size_t ws_size,
                              hipStream_t stream) {
  const float* x  = (const float*)d_in[0];
  const float* Wq = (const float*)d_in[1];
  const float* bq = (const float*)d_in[2];
  const float* Wk = (const float*)d_in[3];
  const float* bk = (const float*)d_in[4];
  const float* Wv = (const float*)d_in[5];
  const float* bv = (const float*)d_in[6];
  float* out = (float*)d_out;

  char* ws = (char*)d_ws;
  short* Xb  = (short*)(ws);                 // 16384x1024 bf16 = 33,554,432 B
  short* Wb  = (short*)(ws + 33554432);      // 3x1024x1024 bf16 = 6,291,456 B
  short* Qb  = (short*)(ws + 39845888);      // 33,554,432 B (pre-scaled by 1/32)
  short* Kb  = (short*)(ws + 73400320);      // 33,554,432 B
  short* Vtb = (short*)(ws + 106954752);     // 33,554,432 B (per-batch transposed [C][T])
  // total ws use: 140,509,184 B

  // 0) convert x + weights to bf16
  cvt_kernel<<<19456, 256, 0, stream>>>(x, Wq, Wk, Wv, Xb, Wb);
  // 1) QKV projection (n-tile fastest for X L2 reuse)
  qkv_gemm<<<dim3(48, 256), 256, 0, stream>>>(Xb, Wb, bq, bk, bv, Qb, Kb, Vtb);
  // 2) flash attention
  flash_attn<<<512, 512, 0, stream>>>(Qb, Kb, Vtb, out);
}

// Round 2
// 928.273 us; speedup vs baseline: 1.7587x; 1.7587x over previous
//
#include <hip/hip_runtime.h>
#include <hip/hip_bf16.h>

// bf16 MFMA fragment types (per cdna_hip_programming.md §3, compile-verified on gfx950)
typedef __attribute__((ext_vector_type(8))) short bf16x8;
typedef __attribute__((ext_vector_type(4))) float floatx4;
typedef __attribute__((ext_vector_type(4))) short short4v;

__device__ inline short f2bf(float f) {
  union { float f; unsigned u; } v; v.f = f;
  unsigned r = v.u + 0x7fffu + ((v.u >> 16) & 1u);  // round-to-nearest-even
  return (short)(r >> 16);
}

// async global->LDS, 16B per lane. LDS dest semantics: wave-uniform base + lane*16.
__device__ inline void gload_lds16(const short* g, short* l) {
  __builtin_amdgcn_global_load_lds(
      (const __attribute__((address_space(1))) unsigned int*)g,
      (__attribute__((address_space(3))) unsigned int*)l, 16, 0, 0);
}

// ---------------- Kernel 0: fp32 -> bf16 conversion (x and the 3 weight mats)
__global__ __launch_bounds__(256) void cvt_kernel(
    const float* __restrict__ x, const float* __restrict__ wq,
    const float* __restrict__ wk, const float* __restrict__ wv,
    short* __restrict__ Xb, short* __restrict__ Wb) {
  long i4 = (long)(blockIdx.x * 256 + threadIdx.x) * 4;
  const float* src; short* dst; long off;
  if (i4 < 16777216L) {
    src = x; dst = Xb; off = i4;
  } else {
    long j = i4 - 16777216L;
    int mat = (int)(j >> 20);
    src = (mat == 0) ? wq : ((mat == 1) ? wk : wv);
    dst = Wb + ((long)mat << 20);
    off = j & 1048575L;
  }
  float4 v = *(const float4*)(src + off);
  short4v o; o.x = f2bf(v.x); o.y = f2bf(v.y); o.z = f2bf(v.z); o.w = f2bf(v.w);
  *(short4v*)(dst + off) = o;
}

// ---------------- Kernel 1: QKV projection as one NT-GEMM, m97 structure.
// C[m,n] = sum_k X[m,k] * W[n,k],  M=16384, N=3072 (Q|K|V), K=1024.
// 128x128 tile / block, BK=32, 256 thr = 4 waves (2x2), each wave 64x64 = 4x4 MFMA tiles.
// Staging: global_load_lds width=16, contiguous LDS [128][32] (no pad - required by HW).
// Epilogue: fuse bias; Q scaled by 1/32; V written transposed per batch Vtb[b][c][t].
__global__ __launch_bounds__(256) void qkv_gemm(
    const short* __restrict__ Xb, const short* __restrict__ Wb,
    const float* __restrict__ bq, const float* __restrict__ bk,
    const float* __restrict__ bv,
    short* __restrict__ Qb, short* __restrict__ Kb, short* __restrict__ Vtb) {
  __shared__ short As[128 * 32];
  __shared__ short Bs[128 * 32];

  const int tid  = threadIdx.x;
  const int wave = tid >> 6, lane = tid & 63;
  const int quad = lane >> 4, l16 = lane & 15;
  const int wm = wave & 1, wn = wave >> 1;

  const int row0 = blockIdx.x * 128;   // m-tile (fast dim: stream A, reuse B in L2)
  const int col0 = blockIdx.y * 128;   // n-tile

  // staging map: round r (0/1), wave w covers rows r*64 + w*16 + (lane>>2), k-part (lane&3)*8
  const int srow = wave * 16 + (lane >> 2);
  const int skof = (lane & 3) * 8;
  const short* gA0 = Xb + (size_t)(row0 + srow) * 1024 + skof;
  const short* gA1 = gA0 + (size_t)64 * 1024;
  const short* gB0 = Wb + (size_t)(col0 + srow) * 1024 + skof;
  const short* gB1 = gB0 + (size_t)64 * 1024;
  short* lA0 = As + (wave * 16) * 32 + lane * 8;        // = wave base + lane*16B
  short* lA1 = As + (64 + wave * 16) * 32 + lane * 8;
  short* lB0 = Bs + (wave * 16) * 32 + lane * 8;
  short* lB1 = Bs + (64 + wave * 16) * 32 + lane * 8;

  floatx4 acc[4][4] = {};

  for (int k = 0; k < 1024; k += 32) {
    gload_lds16(gA0 + k, lA0);
    gload_lds16(gA1 + k, lA1);
    gload_lds16(gB0 + k, lB0);
    gload_lds16(gB1 + k, lB1);
    __syncthreads();  // compiler drains vmcnt before s_barrier -> LDS tiles ready

    bf16x8 af[4], bfr[4];
#pragma unroll
    for (int mt = 0; mt < 4; mt++)
      af[mt] = *(const bf16x8*)(As + (wm * 64 + mt * 16 + l16) * 32 + quad * 8);
#pragma unroll
    for (int nb = 0; nb < 4; nb++)
      bfr[nb] = *(const bf16x8*)(Bs + (wn * 64 + nb * 16 + l16) * 32 + quad * 8);
#pragma unroll
    for (int mt = 0; mt < 4; mt++)
#pragma unroll
      for (int nb = 0; nb < 4; nb++)
        acc[mt][nb] = __builtin_amdgcn_mfma_f32_16x16x32_bf16(af[mt], bfr[nb], acc[mt][nb], 0, 0, 0);
    __syncthreads();  // all waves done reading LDS before next stage
  }

  // epilogue: C/D layout row=(lane>>4)*4+reg, col=lane&15
#pragma unroll
  for (int nb = 0; nb < 4; nb++) {
    const int col = col0 + wn * 64 + nb * 16 + l16;
    const int mat = col >> 10;
    const int cn  = col & 1023;
    const float* bias = (mat == 0) ? bq : (mat == 1) ? bk : bv;
    const float bb = bias[cn];
    const float qs = (mat == 0) ? 0.03125f : 1.0f;  // fold 1/sqrt(C) into Q
#pragma unroll
    for (int mt = 0; mt < 4; mt++) {
#pragma unroll
      for (int r = 0; r < 4; r++) {
        const int row = row0 + wm * 64 + mt * 16 + quad * 4 + r;
        short o = f2bf((acc[mt][nb][r] + bb) * qs);
        if (mat == 0)      Qb[(size_t)row * 1024 + cn] = o;
        else if (mat == 1) Kb[(size_t)row * 1024 + cn] = o;
        else {
          int bat = row >> 11, t = row & 2047;
          Vtb[((size_t)bat << 21) + (size_t)cn * 2048 + t] = o;
        }
      }
    }
  }
}

// ---------------- Kernel 2: flash attention, causal. Block = 512 thr (8 waves).
// Q-tile = 32 rows, KV-tile = 64. Wave w: QK^T tile (mi=w&1, ni=w>>1); PV cols [w*128, w*128+128).
__global__ __launch_bounds__(512) void flash_attn(
    const short* __restrict__ Qb, const short* __restrict__ Kb,
    const short* __restrict__ Vtb, float* __restrict__ out) {
  __shared__ float Sf[32][66];
  __shared__ short Pb[32][72];
  __shared__ float mrow[32], lrow[32], arow[32];
  __shared__ float red[32][16];

  const int b  = blockIdx.x & 7;
  const int qt = 63 - (blockIdx.x >> 3);  // heavy (late) q-tiles first: causal load balance
  const int qbase = qt * 32;
  const int tid = threadIdx.x;
  const int wave = tid >> 6, lane = tid & 63;
  const int quad = lane >> 4, l16 = lane & 15;

  const short* Qp = Qb + ((size_t)b << 21);
  const short* Kp = Kb + ((size_t)b << 21);
  const short* Vp = Vtb + ((size_t)b << 21);

  if (tid < 32) { mrow[tid] = -1e30f; lrow[tid] = 0.0f; }

  floatx4 O[2][8] = {};

  const int mi = wave & 1, ni = wave >> 1;
  const short* qptr  = Qp + (size_t)(qbase + mi * 16 + l16) * 1024 + quad * 8;
  const short* kptr0 = Kp + (size_t)(ni * 16 + l16) * 1024 + quad * 8;

  const int row = tid >> 4, sub = tid & 15;
  const int gr = qbase + row;
  const int ntiles = (qbase + 31) / 64 + 1;
  const int vc0 = wave * 128;

  __syncthreads();

  for (int kt = 0; kt < ntiles; kt++) {
    const int kvbase = kt * 64;
    // ---- S = (Q/32) K^T : each wave one 16x16 tile, loop over d
    floatx4 s4 = {};
    const short* kptr = kptr0 + (size_t)kvbase * 1024;
#pragma unroll 4
    for (int d = 0; d < 1024; d += 32) {
      bf16x8 qa = *(const bf16x8*)(qptr + d);
      bf16x8 kb = *(const bf16x8*)(kptr + d);
      s4 = __builtin_amdgcn_mfma_f32_16x16x32_bf16(qa, kb, s4, 0, 0, 0);
    }
#pragma unroll
    for (int r = 0; r < 4; r++)
      Sf[mi * 16 + quad * 4 + r][ni * 16 + l16] = s4[r];
    __syncthreads();  // B0

    // ---- online softmax: thread -> (row = tid>>4, 4 cols)
    float sv[4], mx = -1e30f;
#pragma unroll
    for (int j = 0; j < 4; j++) {
      const int c = sub * 4 + j;
      float v = Sf[row][c];
      if (kvbase + c > gr) v = -1e30f;  // causal mask
      sv[j] = v;
      mx = fmaxf(mx, v);
    }
    red[row][sub] = mx;
    __syncthreads();  // B1
    if (sub == 0) {
      float mo = mrow[row], mn = mo;
#pragma unroll
      for (int k2 = 0; k2 < 16; k2++) mn = fmaxf(mn, red[row][k2]);
      mrow[row] = mn;
      arow[row] = __expf(mo - mn);
    }
    __syncthreads();  // B2
    const float mn = mrow[row];
    float ps = 0.0f;
#pragma unroll
    for (int j = 0; j < 4; j++) {
      float p = __expf(sv[j] - mn);
      ps += p;
      Pb[row][sub * 4 + j] = f2bf(p);
    }
    red[row][sub] = ps;
    __syncthreads();  // B3
    if (sub == 0) {
      float s = 0.0f;
#pragma unroll
      for (int k2 = 0; k2 < 16; k2++) s += red[row][k2];
      lrow[row] = lrow[row] * arow[row] + s;
    }
    __syncthreads();  // B4: Pb + arow ready for all waves

    // ---- O = diag(alpha) O + P V  (wave owns 128 V columns; V is pre-transposed)
    float al[2][4];
#pragma unroll
    for (int m2 = 0; m2 < 2; m2++)
#pragma unroll
      for (int r = 0; r < 4; r++)
        al[m2][r] = arow[m2 * 16 + quad * 4 + r];
#pragma unroll
    for (int m2 = 0; m2 < 2; m2++)
#pragma unroll
      for (int nb = 0; nb < 8; nb++)
#pragma unroll
        for (int r = 0; r < 4; r++)
          O[m2][nb][r] *= al[m2][r];

#pragma unroll
    for (int kc = 0; kc < 2; kc++) {
      bf16x8 pa0 = *(const bf16x8*)&Pb[l16][kc * 32 + quad * 8];
      bf16x8 pa1 = *(const bf16x8*)&Pb[16 + l16][kc * 32 + quad * 8];
#pragma unroll
      for (int nb = 0; nb < 8; nb++) {
        const short* vptr = Vp + (size_t)(vc0 + nb * 16 + l16) * 2048 + kvbase + kc * 32 + quad * 8;
        bf16x8 vb = *(const bf16x8*)vptr;
        O[0][nb] = __builtin_amdgcn_mfma_f32_16x16x32_bf16(pa0, vb, O[0][nb], 0, 0, 0);
        O[1][nb] = __builtin_amdgcn_mfma_f32_16x16x32_bf16(pa1, vb, O[1][nb], 0, 0, 0);
      }
    }
  }

  __syncthreads();
  float linv[2][4];
#pragma unroll
  for (int m2 = 0; m2 < 2; m2++)
#pragma unroll
    for (int r = 0; r < 4; r++)
      linv[m2][r] = 1.0f / lrow[m2 * 16 + quad * 4 + r];
#pragma unroll
  for (int m2 = 0; m2 < 2; m2++)
#pragma unroll
    for (int nb = 0; nb < 8; nb++)
#pragma unroll
      for (int r = 0; r < 4; r++) {
        const int rr = qbase + m2 * 16 + quad * 4 + r;
        const int cc = vc0 + nb * 16 + l16;
        out[((size_t)b * 2048 + rr) * 1024 + cc] = O[m2][nb][r] * linv[m2][r];
      }
}

extern "C" void kernel_launch(void* const* d_in, const int* in_sizes, int n_in,
                              void* d_out, int out_size, void* d_ws, size_t ws_size,
                              hipStream_t stream) {
  const float* x  = (const float*)d_in[0];
  const float* Wq = (const float*)d_in[1];
  const float* bq = (const float*)d_in[2];
  const float* Wk = (const float*)d_in[3];
  const float* bk = (const float*)d_in[4];
  const float* Wv = (const float*)d_in[5];
  const float* bv = (const float*)d_in[6];
  float* out = (float*)d_out;

  char* ws = (char*)d_ws;
  short* Xb  = (short*)(ws);                 // 16384x1024 bf16 = 33,554,432 B
  short* Wb  = (short*)(ws + 33554432);      // 3x1024x1024 bf16 = 6,291,456 B (Wq|Wk|Wv rows)
  short* Qb  = (short*)(ws + 39845888);      // 33,554,432 B (pre-scaled by 1/32)
  short* Kb  = (short*)(ws + 73400320);      // 33,554,432 B
  short* Vtb = (short*)(ws + 106954752);     // 33,554,432 B (per-batch transposed [C][T])
  // total ws use: 140,509,184 B

  // 0) convert x + weights to bf16
  cvt_kernel<<<19456, 256, 0, stream>>>(x, Wq, Wk, Wv, Xb, Wb);
  // 1) QKV projection: one 16384x3072x1024 NT-GEMM, m-tile fast (B-tile L2 reuse)
  qkv_gemm<<<dim3(128, 24), 256, 0, stream>>>(Xb, Wb, bq, bk, bv, Qb, Kb, Vtb);
  // 2) flash attention
  flash_attn<<<512, 512, 0, stream>>>(Qb, Kb, Vtb, out);
}